// Round 2
// baseline (357.092 us; speedup 1.0000x reference)
//
#include <hip/hip_runtime.h>
#include <hip/hip_bf16.h>

#define B_  32
#define T_  1024
#define C_  8
#define K_  10
#define LH_ 32

// ---------------------------------------------------------------------------
// K1: h[b,t,:] = x[b,t,:] @ pw + pb  (fp32), sq[b,t] = ||h||^2 ; zero acc
// one thread per (row, i): 32768*32 = 1M threads
// ---------------------------------------------------------------------------
__global__ __launch_bounds__(256) void k_project(
    const float* __restrict__ x,
    const float* __restrict__ pw,
    const float* __restrict__ pb,
    float* __restrict__ h, float* __restrict__ sq, float* __restrict__ acc)
{
    int gid = blockIdx.x * 256 + threadIdx.x;
    if (gid < B_ * LH_) acc[gid] = 0.f;   // zero per-batch tanh accumulators
    int row = gid >> 5;                   // b*1024 + t
    int i   = gid & 31;
    const float* xr = x + (size_t)row * C_;
    float4 x0 = *(const float4*)xr;
    float4 x1 = *(const float4*)(xr + 4);
    float hv = pb[i];
    hv = fmaf(x0.x, pw[0 * LH_ + i], hv);
    hv = fmaf(x0.y, pw[1 * LH_ + i], hv);
    hv = fmaf(x0.z, pw[2 * LH_ + i], hv);
    hv = fmaf(x0.w, pw[3 * LH_ + i], hv);
    hv = fmaf(x1.x, pw[4 * LH_ + i], hv);
    hv = fmaf(x1.y, pw[5 * LH_ + i], hv);
    hv = fmaf(x1.z, pw[6 * LH_ + i], hv);
    hv = fmaf(x1.w, pw[7 * LH_ + i], hv);
    h[(size_t)row * LH_ + i] = hv;
    float e = hv * hv;
#pragma unroll
    for (int off = 1; off < 32; off <<= 1) e += __shfl_xor(e, off, 64);
    if (i == 0) sq[row] = e;
}

// ---------------------------------------------------------------------------
// K2: per (b,t): top-10 nearest neighbors by d2 = sq_t + sq_s - 2 h_t.h_s,
// Gaussian weights from fp32 recomputed ||diff||^2, smooth, lap, tanh,
// accumulate per-batch sum of tanh(lap).
// Block = 4 waves, each wave handles 2 consecutive t of one batch.
// ---------------------------------------------------------------------------
#define STILE 128
#define SPAD  36   // padded LDS row stride (floats); keeps b128 16B-aligned

__global__ __launch_bounds__(256) void k_laplace(
    const float* __restrict__ h, const float* __restrict__ sq,
    float* __restrict__ acc)
{
    __shared__ float tile[STILE * SPAD];   // 18 KB s-tile
    __shared__ float wacc[4 * 32];         // per-wave tanh accumulators
    __shared__ float qbuf[8 * 32];         // per-wave query rows (lane-indexable)

    const int tid = threadIdx.x;
    const int wv  = tid >> 6;
    const int ln  = tid & 63;
    const int b   = blockIdx.x >> 7;            // 128 blocks per batch
    const int t0  = (blockIdx.x & 127) * 8;     // 8 t per block
    const int tA  = t0 + wv * 2;
    const int tB  = tA + 1;

    const float* hb  = h  + (size_t)b * T_ * LH_;
    const float* sqb = sq + b * T_;

    if (ln < 32) {
        qbuf[(wv * 2 + 0) * 32 + ln] = hb[tA * LH_ + ln];
        qbuf[(wv * 2 + 1) * 32 + ln] = hb[tB * LH_ + ln];
    }
    float qA[32], qB[32];
#pragma unroll
    for (int i = 0; i < 32; ++i) { qA[i] = hb[tA * LH_ + i]; qB[i] = hb[tB * LH_ + i]; }
    const float sqA = sqb[tA], sqB = sqb[tB];

    float vA[16], vB[16];   // d2 row slices: chunk c holds s = c*64 + ln

    for (int tl = 0; tl < T_ / STILE; ++tl) {
        const int s_base = tl * STILE;
        __syncthreads();
        // cooperative stage: 128 rows x 32 floats as float4 (1024 f4 / 256 thr)
#pragma unroll
        for (int u = 0; u < 4; ++u) {
            int e4 = u * 256 + tid;
            int r  = e4 >> 3, c4 = e4 & 7;
            float4 val = *(const float4*)(hb + (size_t)(s_base + r) * LH_ + c4 * 4);
            *(float4*)&tile[r * SPAD + c4 * 4] = val;
        }
        __syncthreads();
#pragma unroll
        for (int sub = 0; sub < 2; ++sub) {
            const int sr = sub * 64 + ln;
            const int s  = s_base + sr;
            const float* hs = &tile[sr * SPAD];
            float dA = 0.f, dB = 0.f;
#pragma unroll
            for (int q4 = 0; q4 < 8; ++q4) {
                float4 hv4 = *(const float4*)(hs + q4 * 4);
                dA = fmaf(hv4.x, qA[q4 * 4 + 0], dA); dB = fmaf(hv4.x, qB[q4 * 4 + 0], dB);
                dA = fmaf(hv4.y, qA[q4 * 4 + 1], dA); dB = fmaf(hv4.y, qB[q4 * 4 + 1], dB);
                dA = fmaf(hv4.z, qA[q4 * 4 + 2], dA); dB = fmaf(hv4.z, qB[q4 * 4 + 2], dB);
                dA = fmaf(hv4.w, qA[q4 * 4 + 3], dA); dB = fmaf(hv4.w, qB[q4 * 4 + 3], dB);
            }
            const float sqs = sqb[s];
            float d2A = fmaxf(sqA + sqs - 2.f * dA, 0.f);
            float d2B = fmaxf(sqB + sqs - 2.f * dB, 0.f);
            if (s == tA) d2A = 3.0e38f;   // exclude self (ref adds 1e18 on diag)
            if (s == tB) d2B = 3.0e38f;
            vA[tl * 2 + sub] = d2A;
            vB[tl * 2 + sub] = d2B;
        }
    }

    float racc = 0.f;

    auto process = [&](float (&v)[16], int qslot) {
        int sk[K_];
        // 10 rounds of global argmin (value, then lower index on ties -- jax top_k)
#pragma unroll
        for (int r = 0; r < K_; ++r) {
            float m = v[0]; int mc = 0;
#pragma unroll
            for (int c = 1; c < 16; ++c) {
                bool p = v[c] < m;
                m  = p ? v[c] : m;
                mc = p ? c : mc;
            }
            int mi = mc * 64 + ln;   // global s index
#pragma unroll
            for (int off = 32; off >= 1; off >>= 1) {
                float om = __shfl_xor(m,  off, 64);
                int   oi = __shfl_xor(mi, off, 64);
                bool p = (om < m) || (om == m && oi < mi);
                m  = p ? om : m;
                mi = p ? oi : mi;
            }
            sk[r] = mi;              // uniform across wave
            if ((mi & 63) == ln) {
                int c = mi >> 6;
#pragma unroll
                for (int cc = 0; cc < 16; ++cc) if (cc == c) v[cc] = 3.0e38f;
            }
        }
        // weights + smooth + laplace + tanh (lanes 0..31 own dim i; upper half dup)
        const int i = ln & 31;
        const float qi = qbuf[qslot * 32 + i];
        float nv[K_], d2p[K_];
#pragma unroll
        for (int k = 0; k < K_; ++k) {
            float hvv = hb[(size_t)sk[k] * LH_ + i];
            nv[k] = hvv;
            float df = hvv - qi;
            float e = df * df;
#pragma unroll
            for (int off = 1; off < 32; off <<= 1) e += __shfl_xor(e, off, 64);
            d2p[k] = e;
        }
        float W = 0.f, w[K_];
#pragma unroll
        for (int k = 0; k < K_; ++k) { w[k] = __expf(-0.5f * d2p[k]); W += w[k]; }
        float invW = 1.f / (W + 1e-8f);
        float sm = 0.f;
#pragma unroll
        for (int k = 0; k < K_; ++k) sm = fmaf(w[k] * invW, nv[k], sm);
        racc += tanhf(qi - sm);
    };

    process(vA, wv * 2 + 0);
    process(vB, wv * 2 + 1);

    if (ln < 32) wacc[wv * 32 + ln] = racc;
    __syncthreads();
    if (tid < 32) {
        float tot = wacc[tid] + wacc[32 + tid] + wacc[64 + tid] + wacc[96 + tid];
        atomicAdd(&acc[b * LH_ + tid], tot);
    }
}

// ---------------------------------------------------------------------------
// K3: per-batch TCN tail (receptive field 28 -> only t in [995,1023]),
// head, lap_pool = (acc/T)@ow + ob, fusion MLP, fp32 output.
// ---------------------------------------------------------------------------
struct TcnW { const float *c1w, *c1b, *c2w, *c2b, *dw, *db; };
struct HeadW {
    const float *ow, *ob, *head_w, *head_b;
    const float *f1w, *f1b, *f2w, *f2b, *r1w, *r1b, *r2w, *r2b;
};

__global__ __launch_bounds__(256) void k_tail(
    const float* __restrict__ x,
    const float* __restrict__ acc,
    TcnW w0, TcnW w1, TcnW w2, HeadW hw,
    float* __restrict__ out)
{
    const int b   = blockIdx.x;
    const int tid = threadIdx.x;
    __shared__ float xt[29 * 8];    // x[b, 995..1023, :]
    __shared__ float a0[27 * 32];   // block0 conv1 out, t = 997..1023
    __shared__ float o0[25 * 32];   // block0 out,       t = 999..1023
    __shared__ float a1[21 * 64];   // block1 conv1 out, t = 1003..1023
    __shared__ float o1[17 * 64];   // block1 out,       t = 1007..1023
    __shared__ float a2[9 * 128];   // block2 conv1 out, t = 1015..1023
    __shared__ float yv[128];       // block2 out at t = 1023
    __shared__ float v96[96];       // [lap_pool(32) | tcn_feat(64)]
    __shared__ float h1[256], h2[256], h3[128];

    if (tid < 232) {
        int r = tid >> 3, c = tid & 7;
        xt[tid] = x[((size_t)b * T_ + (995 + r)) * C_ + c];
    }
    __syncthreads();

    for (int e = tid; e < 27 * 32; e += 256) {       // b0 conv1 (d=1, 8->32)
        int r = e >> 5, o = e & 31;
        float s = w0.c1b[o];
#pragma unroll
        for (int j = 0; j < 3; ++j)
#pragma unroll
            for (int i = 0; i < 8; ++i)
                s = fmaf(w0.c1w[o * 24 + i * 3 + j], xt[(r + j) * 8 + i], s);
        a0[e] = fmaxf(s, 0.f);
    }
    __syncthreads();

    for (int e = tid; e < 25 * 32; e += 256) {       // b0 conv2 + downsample
        int r = e >> 5, o = e & 31;
        float s = w0.c2b[o];
        for (int j = 0; j < 3; ++j)
            for (int i = 0; i < 32; ++i)
                s = fmaf(w0.c2w[o * 96 + i * 3 + j], a0[(r + j) * 32 + i], s);
        s = fmaxf(s, 0.f);
        float res = w0.db[o];
#pragma unroll
        for (int i = 0; i < 8; ++i)
            res = fmaf(w0.dw[o * 8 + i], xt[(r + 4) * 8 + i], res);
        o0[e] = fmaxf(s + res, 0.f);
    }
    __syncthreads();

    for (int e = tid; e < 21 * 64; e += 256) {       // b1 conv1 (d=2, 32->64)
        int r = e >> 6, o = e & 63;
        float s = w1.c1b[o];
        for (int j = 0; j < 3; ++j)
            for (int i = 0; i < 32; ++i)
                s = fmaf(w1.c1w[o * 96 + i * 3 + j], o0[(r + 2 * j) * 32 + i], s);
        a1[e] = fmaxf(s, 0.f);
    }
    __syncthreads();

    for (int e = tid; e < 17 * 64; e += 256) {       // b1 conv2 + downsample
        int r = e >> 6, o = e & 63;
        float s = w1.c2b[o];
        for (int j = 0; j < 3; ++j)
            for (int i = 0; i < 64; ++i)
                s = fmaf(w1.c2w[o * 192 + i * 3 + j], a1[(r + 2 * j) * 64 + i], s);
        s = fmaxf(s, 0.f);
        float res = w1.db[o];
        for (int i = 0; i < 32; ++i)
            res = fmaf(w1.dw[o * 32 + i], o0[(r + 8) * 32 + i], res);
        o1[e] = fmaxf(s + res, 0.f);
    }
    __syncthreads();

    for (int e = tid; e < 9 * 128; e += 256) {       // b2 conv1 (d=4, 64->128)
        int r = e >> 7, o = e & 127;
        float s = w2.c1b[o];
        for (int j = 0; j < 3; ++j)
            for (int i = 0; i < 64; ++i)
                s = fmaf(w2.c1w[o * 192 + i * 3 + j], o1[(r + 4 * j) * 64 + i], s);
        a2[e] = fmaxf(s, 0.f);
    }
    __syncthreads();

    if (tid < 128) {                                  // b2 conv2 + ds at t=1023
        int o = tid;
        float s = w2.c2b[o];
        for (int j = 0; j < 3; ++j)
            for (int i = 0; i < 128; ++i)
                s = fmaf(w2.c2w[o * 384 + i * 3 + j], a2[(4 * j) * 128 + i], s);
        s = fmaxf(s, 0.f);
        float res = w2.db[o];
        for (int i = 0; i < 64; ++i)
            res = fmaf(w2.dw[o * 64 + i], o1[16 * 64 + i], res);
        yv[o] = fmaxf(s + res, 0.f);
    } else if (tid < 160) {                           // lap_pool = (acc/T)@ow + ob
        int j = tid - 128;
        float s = hw.ob[j];
        for (int i = 0; i < 32; ++i)
            s = fmaf(acc[b * 32 + i] * (1.f / 1024.f), hw.ow[i * 32 + j], s);
        v96[j] = s;
    }
    __syncthreads();

    if (tid < 64) {                                   // tcn_feat = y@head_w + head_b
        float s = hw.head_b[tid];
        for (int i = 0; i < 128; ++i)
            s = fmaf(yv[i], hw.head_w[i * 64 + tid], s);
        v96[32 + tid] = s;
    }
    __syncthreads();

    {                                                 // f1: 96 -> 256, relu
        float s = hw.f1b[tid];
        for (int i = 0; i < 96; ++i)
            s = fmaf(v96[i], hw.f1w[i * 256 + tid], s);
        h1[tid] = fmaxf(s, 0.f);
    }
    __syncthreads();
    {                                                 // f2: 256 -> 256, relu
        float s = hw.f2b[tid];
        for (int i = 0; i < 256; ++i)
            s = fmaf(h1[i], hw.f2w[i * 256 + tid], s);
        h2[tid] = fmaxf(s, 0.f);
    }
    __syncthreads();
    if (tid < 128) {                                  // r1: 256 -> 128, relu
        float s = hw.r1b[tid];
        for (int i = 0; i < 256; ++i)
            s = fmaf(h2[i], hw.r1w[i * 128 + tid], s);
        h3[tid] = fmaxf(s, 0.f);
    }
    __syncthreads();
    if (tid < 10) {                                   // r2: 128 -> 10
        float s = hw.r2b[tid];
        for (int i = 0; i < 128; ++i)
            s = fmaf(h3[i], hw.r2w[i * 10 + tid], s);
        out[b * 10 + tid] = s;
    }
}

// ---------------------------------------------------------------------------
extern "C" void kernel_launch(void* const* d_in, const int* in_sizes, int n_in,
                              void* d_out, int out_size, void* d_ws, size_t ws_size,
                              hipStream_t stream)
{
    const float* x  = (const float*)d_in[0];
    const float* pw = (const float*)d_in[1];
    const float* pb = (const float*)d_in[2];

    TcnW w0 = { (const float*)d_in[5],  (const float*)d_in[6],
                (const float*)d_in[7],  (const float*)d_in[8],
                (const float*)d_in[9],  (const float*)d_in[10] };
    TcnW w1 = { (const float*)d_in[11], (const float*)d_in[12],
                (const float*)d_in[13], (const float*)d_in[14],
                (const float*)d_in[15], (const float*)d_in[16] };
    TcnW w2 = { (const float*)d_in[17], (const float*)d_in[18],
                (const float*)d_in[19], (const float*)d_in[20],
                (const float*)d_in[21], (const float*)d_in[22] };
    HeadW hw = { (const float*)d_in[3],  (const float*)d_in[4],
                 (const float*)d_in[23], (const float*)d_in[24],
                 (const float*)d_in[25], (const float*)d_in[26],
                 (const float*)d_in[27], (const float*)d_in[28],
                 (const float*)d_in[29], (const float*)d_in[30],
                 (const float*)d_in[31], (const float*)d_in[32] };

    float* h   = (float*)d_ws;                    // B*T*32 fp32 = 4 MB
    float* sq  = h  + (size_t)B_ * T_ * LH_;      // B*T fp32    = 128 KB
    float* acc = sq + (size_t)B_ * T_;            // B*32 fp32   = 4 KB

    k_project<<<(B_ * T_ * LH_) / 256, 256, 0, stream>>>(x, pw, pb, h, sq, acc);
    k_laplace<<<(B_ * T_) / 8, 256, 0, stream>>>(h, sq, acc);
    k_tail<<<B_, 256, 0, stream>>>(x, acc, w0, w1, w2, hw, (float*)d_out);
}

// Round 3
// 325.782 us; speedup vs baseline: 1.0961x; 1.0961x over previous
//
#include <hip/hip_runtime.h>
#include <hip/hip_bf16.h>

#define B_  32
#define T_  1024
#define C_  8
#define K_  10
#define LH_ 32

// ---------------------------------------------------------------------------
// K1: h[b,t,:] = x[b,t,:] @ pw + pb  (fp32), sq[b,t] = ||h||^2 ; zero acc
// ---------------------------------------------------------------------------
__global__ __launch_bounds__(256) void k_project(
    const float* __restrict__ x,
    const float* __restrict__ pw,
    const float* __restrict__ pb,
    float* __restrict__ h, float* __restrict__ sq, float* __restrict__ acc)
{
    int gid = blockIdx.x * 256 + threadIdx.x;
    if (gid < B_ * LH_) acc[gid] = 0.f;   // zero per-batch tanh accumulators
    int row = gid >> 5;                   // b*1024 + t
    int i   = gid & 31;
    const float* xr = x + (size_t)row * C_;
    float4 x0 = *(const float4*)xr;
    float4 x1 = *(const float4*)(xr + 4);
    float hv = pb[i];
    hv = fmaf(x0.x, pw[0 * LH_ + i], hv);
    hv = fmaf(x0.y, pw[1 * LH_ + i], hv);
    hv = fmaf(x0.z, pw[2 * LH_ + i], hv);
    hv = fmaf(x0.w, pw[3 * LH_ + i], hv);
    hv = fmaf(x1.x, pw[4 * LH_ + i], hv);
    hv = fmaf(x1.y, pw[5 * LH_ + i], hv);
    hv = fmaf(x1.z, pw[6 * LH_ + i], hv);
    hv = fmaf(x1.w, pw[7 * LH_ + i], hv);
    h[(size_t)row * LH_ + i] = hv;
    float e = hv * hv;
#pragma unroll
    for (int off = 1; off < 32; off <<= 1) e += __shfl_xor(e, off, 64);
    if (i == 0) sq[row] = e;
}

// ---------------------------------------------------------------------------
// K2: top-10 NN per (b,t) via packed u32 keys (d2 mantissa-truncated | index),
// then fp32 Gaussian weights / smooth / tanh, per-batch accumulation.
// ---------------------------------------------------------------------------
#define STILE 128
#define SPAD  36

__global__ __launch_bounds__(256) void k_laplace(
    const float* __restrict__ h, const float* __restrict__ sq,
    float* __restrict__ acc)
{
    __shared__ float tile[STILE * SPAD];
    __shared__ float wacc[4 * 32];
    __shared__ float qbuf[8 * 32];

    const int tid = threadIdx.x;
    const int wv  = tid >> 6;
    const int ln  = tid & 63;
    const int b   = blockIdx.x >> 7;
    const int t0  = (blockIdx.x & 127) * 8;
    const int tA  = t0 + wv * 2;
    const int tB  = tA + 1;

    const float* hb  = h  + (size_t)b * T_ * LH_;
    const float* sqb = sq + b * T_;

    if (ln < 32) {
        qbuf[(wv * 2 + 0) * 32 + ln] = hb[tA * LH_ + ln];
        qbuf[(wv * 2 + 1) * 32 + ln] = hb[tB * LH_ + ln];
    }
    float qA[32], qB[32];
#pragma unroll
    for (int i = 0; i < 32; ++i) { qA[i] = hb[tA * LH_ + i]; qB[i] = hb[tB * LH_ + i]; }
    const float sqA = sqb[tA], sqB = sqb[tB];

    unsigned kA[16], kB[16];   // packed keys: chunk c holds s = c*64 + ln

    for (int tl = 0; tl < T_ / STILE; ++tl) {
        const int s_base = tl * STILE;
        __syncthreads();
#pragma unroll
        for (int u = 0; u < 4; ++u) {
            int e4 = u * 256 + tid;
            int r  = e4 >> 3, c4 = e4 & 7;
            float4 val = *(const float4*)(hb + (size_t)(s_base + r) * LH_ + c4 * 4);
            *(float4*)&tile[r * SPAD + c4 * 4] = val;
        }
        __syncthreads();
#pragma unroll
        for (int sub = 0; sub < 2; ++sub) {
            const int sr = sub * 64 + ln;
            const int s  = s_base + sr;
            const float* hs = &tile[sr * SPAD];
            float dA = 0.f, dB = 0.f;
#pragma unroll
            for (int q4 = 0; q4 < 8; ++q4) {
                float4 hv4 = *(const float4*)(hs + q4 * 4);
                dA = fmaf(hv4.x, qA[q4 * 4 + 0], dA); dB = fmaf(hv4.x, qB[q4 * 4 + 0], dB);
                dA = fmaf(hv4.y, qA[q4 * 4 + 1], dA); dB = fmaf(hv4.y, qB[q4 * 4 + 1], dB);
                dA = fmaf(hv4.z, qA[q4 * 4 + 2], dA); dB = fmaf(hv4.z, qB[q4 * 4 + 2], dB);
                dA = fmaf(hv4.w, qA[q4 * 4 + 3], dA); dB = fmaf(hv4.w, qB[q4 * 4 + 3], dB);
            }
            const float sqs = sqb[s];
            float d2A = fmaxf(sqA + sqs - 2.f * dA, 0.f);
            float d2B = fmaxf(sqB + sqs - 2.f * dB, 0.f);
            // pack: high 22 bits of d2 (monotone for d2>=0) | 10-bit index.
            unsigned keyA = (__float_as_uint(d2A) & 0xFFFFFC00u) | (unsigned)s;
            unsigned keyB = (__float_as_uint(d2B) & 0xFFFFFC00u) | (unsigned)s;
            if (s == tA) keyA = 0xFFFFFC00u | (unsigned)s;   // self -> +inf-ish
            if (s == tB) keyB = 0xFFFFFC00u | (unsigned)s;
            kA[tl * 2 + sub] = keyA;
            kB[tl * 2 + sub] = keyB;
        }
    }

    float racc = 0.f;

    auto process = [&](unsigned (&kk)[16], int qslot) {
        int sk[K_];
        unsigned gm[4];
#pragma unroll
        for (int g = 0; g < 4; ++g)
            gm[g] = min(min(kk[4 * g], kk[4 * g + 1]), min(kk[4 * g + 2], kk[4 * g + 3]));
        unsigned lm = min(min(gm[0], gm[1]), min(gm[2], gm[3]));
#pragma unroll
        for (int r = 0; r < K_; ++r) {
            unsigned m = lm;
#pragma unroll
            for (int off = 32; off >= 1; off >>= 1)
                m = min(m, (unsigned)__shfl_xor((int)m, off, 64));
            unsigned mu = (unsigned)__builtin_amdgcn_readfirstlane((int)m);
            int s_win = (int)(mu & 1023u);
            sk[r] = s_win;
            const int c = s_win >> 6;                 // wave-uniform chunk
            const bool winlane = ((s_win & 63) == ln);
#pragma unroll
            for (int cc = 0; cc < 16; ++cc) if (cc == c) {
                kk[cc] = winlane ? 0xFFFFFFFFu : kk[cc];
                const int g = cc >> 2;
                gm[g] = min(min(kk[4 * g], kk[4 * g + 1]), min(kk[4 * g + 2], kk[4 * g + 3]));
            }
            lm = min(min(gm[0], gm[1]), min(gm[2], gm[3]));
        }
        // exact fp32 weights from recomputed ||diff||^2 (matches reference math)
        const int i = ln & 31;
        const float qi = qbuf[qslot * 32 + i];
        float nv[K_], d2p[K_];
#pragma unroll
        for (int k = 0; k < K_; ++k) {
            float hvv = hb[(size_t)sk[k] * LH_ + i];
            nv[k] = hvv;
            float df = hvv - qi;
            float e = df * df;
#pragma unroll
            for (int off = 1; off < 32; off <<= 1) e += __shfl_xor(e, off, 64);
            d2p[k] = e;
        }
        float W = 0.f, w[K_];
#pragma unroll
        for (int k = 0; k < K_; ++k) { w[k] = __expf(-0.5f * d2p[k]); W += w[k]; }
        float invW = 1.f / (W + 1e-8f);
        float sm = 0.f;
#pragma unroll
        for (int k = 0; k < K_; ++k) sm = fmaf(w[k] * invW, nv[k], sm);
        racc += tanhf(qi - sm);
    };

    process(kA, wv * 2 + 0);
    process(kB, wv * 2 + 1);

    if (ln < 32) wacc[wv * 32 + ln] = racc;
    __syncthreads();
    if (tid < 32) {
        float tot = wacc[tid] + wacc[32 + tid] + wacc[64 + tid] + wacc[96 + tid];
        atomicAdd(&acc[b * LH_ + tid], tot);
    }
}

// ---------------------------------------------------------------------------
// K3: TCN tail with LDS-staged transposed weights (kills uncoalesced reads).
// ---------------------------------------------------------------------------
struct TcnW { const float *c1w, *c1b, *c2w, *c2b, *dw, *db; };
struct HeadW {
    const float *ow, *ob, *head_w, *head_b;
    const float *f1w, *f1b, *f2w, *f2b, *r1w, *r1b, *r2w, *r2b;
};

// stage weights gw[(o, k=K0..K0+KC)] -> wbuf[kk*(CO+1)+o] (padded, transposed)
template<int CI3, int K0, int KC, int CO>
__device__ __forceinline__ void stage_w(const float* __restrict__ gw,
                                        float* __restrict__ wbuf, int tid)
{
#pragma unroll
    for (int f = tid; f < CO * KC; f += 256) {
        int o = f / KC, kk = f - o * KC;
        wbuf[kk * (CO + 1) + o] = gw[o * CI3 + K0 + kk];
    }
}

// one weight-chunk of a dilated conv: stage, sync, accumulate, sync
template<int CI3, int K0, int KC, int CO, int DIL, int ROWS, int STR, int NU>
__device__ __forceinline__ void conv_chunk(const float* __restrict__ gw,
                                           const float* __restrict__ act,
                                           float* __restrict__ wbuf,
                                           float* part, int tid)
{
    stage_w<CI3, K0, KC, CO>(gw, wbuf, tid);
    __syncthreads();
#pragma unroll
    for (int u = 0; u < NU; ++u) {
        int e = tid + u * 256;
        if (e < ROWS * CO) {
            int r = e / CO, o = e - r * CO;
            float s = part[u];
#pragma unroll
            for (int kk = 0; kk < KC; ++kk) {
                const int k = K0 + kk, i = k / 3, j = k - i * 3;
                s = fmaf(wbuf[kk * (CO + 1) + o], act[(r + DIL * j) * STR + i], s);
            }
            part[u] = s;
        }
    }
    __syncthreads();
}

__global__ __launch_bounds__(256) void k_tail(
    const float* __restrict__ x,
    const float* __restrict__ acc,
    TcnW w0, TcnW w1, TcnW w2, HeadW hw,
    float* __restrict__ out)
{
    const int b   = blockIdx.x;
    const int tid = threadIdx.x;
    __shared__ float xt[29 * 8];
    __shared__ float a0[27 * 32];
    __shared__ float o0[25 * 32];
    __shared__ float a1[21 * 64];
    __shared__ float o1[17 * 64];
    __shared__ float a2[9 * 128];
    __shared__ float yv[128];
    __shared__ float v96[96];
    __shared__ float h1[256], h2[256], h3[128];
    __shared__ float wbuf[8448];   // 33 KB padded weight-staging buffer

    if (tid < 232) {
        int r = tid >> 3, c = tid & 7;
        xt[tid] = x[((size_t)b * T_ + (995 + r)) * C_ + c];
    }
    __syncthreads();

    { // ---- b0 conv1: 8 -> 32, d=1, rows 27 ----
        float p[4];
#pragma unroll
        for (int u = 0; u < 4; ++u) {
            int e = tid + u * 256;
            p[u] = (e < 27 * 32) ? w0.c1b[e & 31] : 0.f;
        }
        conv_chunk<24, 0, 24, 32, 1, 27, 8, 4>(w0.c1w, xt, wbuf, p, tid);
#pragma unroll
        for (int u = 0; u < 4; ++u) {
            int e = tid + u * 256;
            if (e < 27 * 32) a0[e] = fmaxf(p[u], 0.f);
        }
        __syncthreads();
    }

    { // ---- b0 conv2 + 1x1 downsample: rows 25 ----
        float p[4];
#pragma unroll
        for (int u = 0; u < 4; ++u) {
            int e = tid + u * 256;
            p[u] = (e < 25 * 32) ? w0.c2b[e & 31] : 0.f;
        }
        conv_chunk<96, 0, 96, 32, 1, 25, 32, 4>(w0.c2w, a0, wbuf, p, tid);
        // stage dw0 transposed: wbuf[i*33+o]
        if (tid < 256) {
            int f = tid;   // 256 = 32*8 exactly
            int o = f >> 3, i = f & 7;
            wbuf[i * 33 + o] = w0.dw[f];
        }
        __syncthreads();
#pragma unroll
        for (int u = 0; u < 4; ++u) {
            int e = tid + u * 256;
            if (e < 25 * 32) {
                int r = e >> 5, o = e & 31;
                float res = w0.db[o];
#pragma unroll
                for (int i = 0; i < 8; ++i)
                    res = fmaf(wbuf[i * 33 + o], xt[(r + 4) * 8 + i], res);
                o0[e] = fmaxf(fmaxf(p[u], 0.f) + res, 0.f);
            }
        }
        __syncthreads();
    }

    { // ---- b1 conv1: 32 -> 64, d=2, rows 21 ----
        float p[6];
#pragma unroll
        for (int u = 0; u < 6; ++u) {
            int e = tid + u * 256;
            p[u] = (e < 21 * 64) ? w1.c1b[e & 63] : 0.f;
        }
        conv_chunk<96, 0, 96, 64, 2, 21, 32, 6>(w1.c1w, o0, wbuf, p, tid);
#pragma unroll
        for (int u = 0; u < 6; ++u) {
            int e = tid + u * 256;
            if (e < 21 * 64) a1[e] = fmaxf(p[u], 0.f);
        }
        __syncthreads();
    }

    { // ---- b1 conv2 + downsample: 64 -> 64, d=2, rows 17 (2 weight chunks) ----
        float p[5];
#pragma unroll
        for (int u = 0; u < 5; ++u) {
            int e = tid + u * 256;
            p[u] = (e < 17 * 64) ? w1.c2b[e & 63] : 0.f;
        }
        conv_chunk<192, 0,  96, 64, 2, 17, 64, 5>(w1.c2w, a1, wbuf, p, tid);
        conv_chunk<192, 96, 96, 64, 2, 17, 64, 5>(w1.c2w, a1, wbuf, p, tid);
        // stage dw1 (64x32) transposed: wbuf[i*65+o]
#pragma unroll
        for (int f = tid; f < 2048; f += 256) {
            int o = f >> 5, i = f & 31;
            wbuf[i * 65 + o] = w1.dw[f];
        }
        __syncthreads();
#pragma unroll
        for (int u = 0; u < 5; ++u) {
            int e = tid + u * 256;
            if (e < 17 * 64) {
                int r = e >> 6, o = e & 63;
                float res = w1.db[o];
#pragma unroll
                for (int i = 0; i < 32; ++i)
                    res = fmaf(wbuf[i * 65 + o], o0[(r + 8) * 32 + i], res);
                o1[e] = fmaxf(fmaxf(p[u], 0.f) + res, 0.f);
            }
        }
        __syncthreads();
    }

    { // ---- b2 conv1: 64 -> 128, d=4, rows 9 (3 weight chunks) ----
        float p[5];
#pragma unroll
        for (int u = 0; u < 5; ++u) {
            int e = tid + u * 256;
            p[u] = (e < 9 * 128) ? w2.c1b[e & 127] : 0.f;
        }
        conv_chunk<192, 0,   64, 128, 4, 9, 64, 5>(w2.c1w, o1, wbuf, p, tid);
        conv_chunk<192, 64,  64, 128, 4, 9, 64, 5>(w2.c1w, o1, wbuf, p, tid);
        conv_chunk<192, 128, 64, 128, 4, 9, 64, 5>(w2.c1w, o1, wbuf, p, tid);
#pragma unroll
        for (int u = 0; u < 5; ++u) {
            int e = tid + u * 256;
            if (e < 9 * 128) a2[e] = fmaxf(p[u], 0.f);
        }
        __syncthreads();
    }

    { // ---- b2 conv2 + downsample at t=1023 only (6 weight chunks) ----
        float p[1];
        p[0] = (tid < 128) ? w2.c2b[tid] : 0.f;
        conv_chunk<384, 0,   64, 128, 4, 1, 128, 1>(w2.c2w, a2, wbuf, p, tid);
        conv_chunk<384, 64,  64, 128, 4, 1, 128, 1>(w2.c2w, a2, wbuf, p, tid);
        conv_chunk<384, 128, 64, 128, 4, 1, 128, 1>(w2.c2w, a2, wbuf, p, tid);
        conv_chunk<384, 192, 64, 128, 4, 1, 128, 1>(w2.c2w, a2, wbuf, p, tid);
        conv_chunk<384, 256, 64, 128, 4, 1, 128, 1>(w2.c2w, a2, wbuf, p, tid);
        conv_chunk<384, 320, 64, 128, 4, 1, 128, 1>(w2.c2w, a2, wbuf, p, tid);
        // stage dw2 (128x64) transposed: wbuf[i*129+o]
#pragma unroll
        for (int f = tid; f < 8192; f += 256) {
            int o = f >> 6, i = f & 63;
            wbuf[i * 129 + o] = w2.dw[f];
        }
        __syncthreads();
        if (tid < 128) {
            float res = w2.db[tid];
#pragma unroll
            for (int i = 0; i < 64; ++i)
                res = fmaf(wbuf[i * 129 + tid], o1[16 * 64 + i], res);
            yv[tid] = fmaxf(fmaxf(p[0], 0.f) + res, 0.f);
        } else if (tid < 160) {            // lap_pool = (acc/T)@ow + ob
            int j = tid - 128;
            float s = hw.ob[j];
            for (int i = 0; i < 32; ++i)
                s = fmaf(acc[b * 32 + i] * (1.f / 1024.f), hw.ow[i * 32 + j], s);
            v96[j] = s;
        }
        __syncthreads();
    }

    if (tid < 64) {                         // tcn_feat = y@head_w + head_b
        float s = hw.head_b[tid];
        for (int i = 0; i < 128; ++i)
            s = fmaf(yv[i], hw.head_w[i * 64 + tid], s);
        v96[32 + tid] = s;
    }
    __syncthreads();

    {                                       // f1: 96 -> 256, relu
        float s = hw.f1b[tid];
        for (int i = 0; i < 96; ++i)
            s = fmaf(v96[i], hw.f1w[i * 256 + tid], s);
        h1[tid] = fmaxf(s, 0.f);
    }
    __syncthreads();
    {                                       // f2: 256 -> 256, relu
        float s = hw.f2b[tid];
        for (int i = 0; i < 256; ++i)
            s = fmaf(h1[i], hw.f2w[i * 256 + tid], s);
        h2[tid] = fmaxf(s, 0.f);
    }
    __syncthreads();
    if (tid < 128) {                        // r1: 256 -> 128, relu
        float s = hw.r1b[tid];
        for (int i = 0; i < 256; ++i)
            s = fmaf(h2[i], hw.r1w[i * 128 + tid], s);
        h3[tid] = fmaxf(s, 0.f);
    }
    __syncthreads();
    if (tid < 10) {                         // r2: 128 -> 10
        float s = hw.r2b[tid];
        for (int i = 0; i < 128; ++i)
            s = fmaf(h3[i], hw.r2w[i * 10 + tid], s);
        out[b * 10 + tid] = s;
    }
}

// ---------------------------------------------------------------------------
extern "C" void kernel_launch(void* const* d_in, const int* in_sizes, int n_in,
                              void* d_out, int out_size, void* d_ws, size_t ws_size,
                              hipStream_t stream)
{
    const float* x  = (const float*)d_in[0];
    const float* pw = (const float*)d_in[1];
    const float* pb = (const float*)d_in[2];

    TcnW w0 = { (const float*)d_in[5],  (const float*)d_in[6],
                (const float*)d_in[7],  (const float*)d_in[8],
                (const float*)d_in[9],  (const float*)d_in[10] };
    TcnW w1 = { (const float*)d_in[11], (const float*)d_in[12],
                (const float*)d_in[13], (const float*)d_in[14],
                (const float*)d_in[15], (const float*)d_in[16] };
    TcnW w2 = { (const float*)d_in[17], (const float*)d_in[18],
                (const float*)d_in[19], (const float*)d_in[20],
                (const float*)d_in[21], (const float*)d_in[22] };
    HeadW hw = { (const float*)d_in[3],  (const float*)d_in[4],
                 (const float*)d_in[23], (const float*)d_in[24],
                 (const float*)d_in[25], (const float*)d_in[26],
                 (const float*)d_in[27], (const float*)d_in[28],
                 (const float*)d_in[29], (const float*)d_in[30],
                 (const float*)d_in[31], (const float*)d_in[32] };

    float* h   = (float*)d_ws;
    float* sq  = h  + (size_t)B_ * T_ * LH_;
    float* acc = sq + (size_t)B_ * T_;

    k_project<<<(B_ * T_ * LH_) / 256, 256, 0, stream>>>(x, pw, pb, h, sq, acc);
    k_laplace<<<(B_ * T_) / 8, 256, 0, stream>>>(h, sq, acc);
    k_tail<<<B_, 256, 0, stream>>>(x, acc, w0, w1, w2, hw, (float*)d_out);
}

// Round 4
// 304.538 us; speedup vs baseline: 1.1726x; 1.0698x over previous
//
#include <hip/hip_runtime.h>
#include <hip/hip_bf16.h>

#define B_  32
#define T_  1024
#define C_  8
#define K_  10
#define LH_ 32

// ---------------------------------------------------------------------------
// workspace layout (floats)
// ---------------------------------------------------------------------------
#define WS_H    0
#define WS_SQ   1048576            // B*T*32
#define WS_ACC  (WS_SQ + 32768)
#define WS_WT   (WS_ACC + 1024)   // transposed weights, 106496 floats
#define WS_A0   (WS_WT + 106496)  // [B][27][32]
#define WS_O0   (WS_A0 + 27648)   // [B][25][32]
#define WS_A1   (WS_O0 + 25600)   // [B][21][64]
#define WS_O1   (WS_A1 + 43008)   // [B][17][64]
#define WS_A2   (WS_O1 + 34816)   // [B][9][128]
#define WS_Y    (WS_A2 + 36864)   // [B][128]

// wT segment offsets (floats within WS_WT)
#define WT_C1_0 0        // [24][32]
#define WT_C2_0 768      // [96][32]
#define WT_DW0  3840     // [8][32]
#define WT_C1_1 4096     // [96][64]
#define WT_C2_1 10240    // [192][64]
#define WT_DW1  22528    // [32][64]
#define WT_C1_2 24576    // [192][128]
#define WT_C2_2 49152    // [384][128]
#define WT_DW2  98304    // [64][128]
#define WT_TOTAL 106496

// ---------------------------------------------------------------------------
// K1: h = x @ pw + pb (fp32), sq = ||h||^2, zero acc
// ---------------------------------------------------------------------------
__global__ __launch_bounds__(256) void k_project(
    const float* __restrict__ x,
    const float* __restrict__ pw,
    const float* __restrict__ pb,
    float* __restrict__ h, float* __restrict__ sq, float* __restrict__ acc)
{
    int gid = blockIdx.x * 256 + threadIdx.x;
    if (gid < B_ * LH_) acc[gid] = 0.f;
    int row = gid >> 5;
    int i   = gid & 31;
    const float* xr = x + (size_t)row * C_;
    float4 x0 = *(const float4*)xr;
    float4 x1 = *(const float4*)(xr + 4);
    float hv = pb[i];
    hv = fmaf(x0.x, pw[0 * LH_ + i], hv);
    hv = fmaf(x0.y, pw[1 * LH_ + i], hv);
    hv = fmaf(x0.z, pw[2 * LH_ + i], hv);
    hv = fmaf(x0.w, pw[3 * LH_ + i], hv);
    hv = fmaf(x1.x, pw[4 * LH_ + i], hv);
    hv = fmaf(x1.y, pw[5 * LH_ + i], hv);
    hv = fmaf(x1.z, pw[6 * LH_ + i], hv);
    hv = fmaf(x1.w, pw[7 * LH_ + i], hv);
    h[(size_t)row * LH_ + i] = hv;
    float e = hv * hv;
#pragma unroll
    for (int off = 1; off < 32; off <<= 1) e += __shfl_xor(e, off, 64);
    if (i == 0) sq[row] = e;
}

// ---------------------------------------------------------------------------
// K2: top-10 NN via packed u32 keys; weights decoded from keys.
// ---------------------------------------------------------------------------
#define STILE 128
#define SPAD  36

__global__ __launch_bounds__(256) void k_laplace(
    const float* __restrict__ h, const float* __restrict__ sq,
    float* __restrict__ acc)
{
    __shared__ float tile[STILE * SPAD];
    __shared__ float wacc[4 * 32];
    __shared__ float qbuf[8 * 32];

    const int tid = threadIdx.x;
    const int wv  = tid >> 6;
    const int ln  = tid & 63;
    const int b   = blockIdx.x >> 7;
    const int t0  = (blockIdx.x & 127) * 8;
    const int tA  = t0 + wv * 2;
    const int tB  = tA + 1;

    const float* hb  = h  + (size_t)b * T_ * LH_;
    const float* sqb = sq + b * T_;

    if (ln < 32) {
        qbuf[(wv * 2 + 0) * 32 + ln] = hb[tA * LH_ + ln];
        qbuf[(wv * 2 + 1) * 32 + ln] = hb[tB * LH_ + ln];
    }
    float qA[32], qB[32];
#pragma unroll
    for (int i = 0; i < 32; ++i) { qA[i] = hb[tA * LH_ + i]; qB[i] = hb[tB * LH_ + i]; }
    const float sqA = sqb[tA], sqB = sqb[tB];

    unsigned kA[16], kB[16];

    for (int tl = 0; tl < T_ / STILE; ++tl) {
        const int s_base = tl * STILE;
        __syncthreads();
#pragma unroll
        for (int u = 0; u < 4; ++u) {
            int e4 = u * 256 + tid;
            int r  = e4 >> 3, c4 = e4 & 7;
            float4 val = *(const float4*)(hb + (size_t)(s_base + r) * LH_ + c4 * 4);
            *(float4*)&tile[r * SPAD + c4 * 4] = val;
        }
        __syncthreads();
#pragma unroll
        for (int sub = 0; sub < 2; ++sub) {
            const int sr = sub * 64 + ln;
            const int s  = s_base + sr;
            const float* hs = &tile[sr * SPAD];
            float dA = 0.f, dB = 0.f;
#pragma unroll
            for (int q4 = 0; q4 < 8; ++q4) {
                float4 hv4 = *(const float4*)(hs + q4 * 4);
                dA = fmaf(hv4.x, qA[q4 * 4 + 0], dA); dB = fmaf(hv4.x, qB[q4 * 4 + 0], dB);
                dA = fmaf(hv4.y, qA[q4 * 4 + 1], dA); dB = fmaf(hv4.y, qB[q4 * 4 + 1], dB);
                dA = fmaf(hv4.z, qA[q4 * 4 + 2], dA); dB = fmaf(hv4.z, qB[q4 * 4 + 2], dB);
                dA = fmaf(hv4.w, qA[q4 * 4 + 3], dA); dB = fmaf(hv4.w, qB[q4 * 4 + 3], dB);
            }
            const float sqs = sqb[s];
            float d2A = fmaxf(sqA + sqs - 2.f * dA, 0.f);
            float d2B = fmaxf(sqB + sqs - 2.f * dB, 0.f);
            unsigned keyA = (__float_as_uint(d2A) & 0xFFFFFC00u) | (unsigned)s;
            unsigned keyB = (__float_as_uint(d2B) & 0xFFFFFC00u) | (unsigned)s;
            if (s == tA) keyA = 0xFFFFFC00u | (unsigned)s;
            if (s == tB) keyB = 0xFFFFFC00u | (unsigned)s;
            kA[tl * 2 + sub] = keyA;
            kB[tl * 2 + sub] = keyB;
        }
    }

    float racc = 0.f;

    auto process = [&](unsigned (&kk)[16], int qslot) {
        int   sk[K_];
        float wk[K_];
        unsigned g2[4];
#pragma unroll
        for (int g = 0; g < 4; ++g)
            g2[g] = min(min(kk[4 * g], kk[4 * g + 1]), min(kk[4 * g + 2], kk[4 * g + 3]));
#pragma unroll
        for (int r = 0; r < K_; ++r) {
            unsigned m = min(min(g2[0], g2[1]), min(g2[2], g2[3]));
#pragma unroll
            for (int off = 32; off >= 1; off >>= 1)
                m = min(m, (unsigned)__shfl_xor((int)m, off, 64));
            unsigned mu = (unsigned)__builtin_amdgcn_readfirstlane((int)m);
            int s_win = (int)(mu & 1023u);
            sk[r] = s_win;
            wk[r] = __expf(-0.5f * __uint_as_float(mu & 0xFFFFFC00u));
            const int c = s_win >> 6;                 // SGPR -> scalar branch
            const bool winlane = ((s_win & 63) == ln);
#pragma unroll
            for (int cc = 0; cc < 16; ++cc) if (cc == c) {
                kk[cc] = winlane ? 0xFFFFFFFFu : kk[cc];
                const int g = cc >> 2;
                g2[g] = min(min(kk[4 * g], kk[4 * g + 1]), min(kk[4 * g + 2], kk[4 * g + 3]));
            }
        }
        const int i = ln & 31;
        const float qi = qbuf[qslot * 32 + i];
        float W = 0.f, sm = 0.f;
#pragma unroll
        for (int k = 0; k < K_; ++k) {
            W += wk[k];
            sm = fmaf(wk[k], hb[(size_t)sk[k] * LH_ + i], sm);
        }
        sm *= __builtin_amdgcn_rcpf(W + 1e-8f);
        float z  = qi - sm;
        float ex = __expf(2.f * z);                   // tanh(z) = 1 - 2/(e^{2z}+1)
        racc += 1.f - 2.f * __builtin_amdgcn_rcpf(ex + 1.f);
    };

    process(kA, wv * 2 + 0);
    process(kB, wv * 2 + 1);

    if (ln < 32) wacc[wv * 32 + ln] = racc;
    __syncthreads();
    if (tid < 32) {
        float tot = wacc[tid] + wacc[32 + tid] + wacc[64 + tid] + wacc[96 + tid];
        atomicAdd(&acc[b * LH_ + tid], tot);
    }
}

// ---------------------------------------------------------------------------
// Weight transpose: wT[k*CO + o] = w[o*K3 + k]  (9 segments, one kernel)
// ---------------------------------------------------------------------------
struct WSegs { const float* src[9]; int k3[9]; int colog2[9]; int off[10]; };

__global__ __launch_bounds__(256) void k_wT(WSegs S, float* __restrict__ wT)
{
    int gid = blockIdx.x * 256 + threadIdx.x;
    if (gid >= WT_TOTAL) return;
#pragma unroll
    for (int s = 0; s < 9; ++s) {
        if (gid >= S.off[s] && gid < S.off[s + 1]) {
            int local = gid - S.off[s];
            int k = local >> S.colog2[s];
            int o = local & ((1 << S.colog2[s]) - 1);
            wT[gid] = S.src[s][o * S.k3[s] + k];
        }
    }
}

// ---------------------------------------------------------------------------
// TCN conv stages (flat, multi-block, coalesced wT reads)
// out[b][r][o] = relu(bias[o] + sum_{i,j} wT[(i*3+j)*CO+o] * in[b][roff+r+DIL*j][i])
// ---------------------------------------------------------------------------
template<int CI, int CO, int DIL, int ROWS>
__global__ __launch_bounds__(256) void k_conv(
    const float* __restrict__ in, int in_bs, int in_roff,
    const float* __restrict__ wT, const float* __restrict__ bias,
    float* __restrict__ out)
{
    const int e = blockIdx.x * 256 + threadIdx.x;
    const int b = blockIdx.y;
    if (e >= ROWS * CO) return;
    const int r = e / CO, o = e % CO;
    const float* inb = in + (size_t)b * in_bs + (size_t)in_roff * CI;
    float s = bias[o];
    for (int i = 0; i < CI; ++i)
#pragma unroll
        for (int j = 0; j < 3; ++j)
            s = fmaf(wT[(i * 3 + j) * CO + o], inb[(r + DIL * j) * CI + i], s);
    out[(size_t)b * (ROWS * CO) + e] = fmaxf(s, 0.f);
}

// conv2 + relu + 1x1-downsample residual + relu
template<int CI, int CO, int DIL, int ROWS, int RCI>
__global__ __launch_bounds__(256) void k_convres(
    const float* __restrict__ in, int in_bs,
    const float* __restrict__ wT2, const float* __restrict__ b2,
    const float* __restrict__ res, int res_bs, int res_roff,
    const float* __restrict__ wTd, const float* __restrict__ db,
    float* __restrict__ out)
{
    const int e = blockIdx.x * 256 + threadIdx.x;
    const int b = blockIdx.y;
    if (e >= ROWS * CO) return;
    const int r = e / CO, o = e % CO;
    const float* inb = in + (size_t)b * in_bs;
    float s = b2[o];
    for (int i = 0; i < CI; ++i)
#pragma unroll
        for (int j = 0; j < 3; ++j)
            s = fmaf(wT2[(i * 3 + j) * CO + o], inb[(r + DIL * j) * CI + i], s);
    s = fmaxf(s, 0.f);
    const float* rb = res + (size_t)b * res_bs + (size_t)(res_roff + r) * RCI;
    float rs = db[o];
    for (int i = 0; i < RCI; ++i)
        rs = fmaf(wTd[i * CO + o], rb[i], rs);
    out[(size_t)b * (ROWS * CO) + e] = fmaxf(s + rs, 0.f);
}

// ---------------------------------------------------------------------------
// Head: lap_pool@ow, TCN head, fusion MLP (one block per batch)
// ---------------------------------------------------------------------------
struct HeadW {
    const float *ow, *ob, *head_w, *head_b;
    const float *f1w, *f1b, *f2w, *f2b, *r1w, *r1b, *r2w, *r2b;
};

__global__ __launch_bounds__(256) void k_head(
    const float* __restrict__ y, const float* __restrict__ acc,
    HeadW hw, float* __restrict__ out)
{
    const int b = blockIdx.x, tid = threadIdx.x;
    __shared__ float yv[128], v96[96], h1[256], h2[256], h3[128];

    if (tid < 128) yv[tid] = y[b * 128 + tid];
    else if (tid < 160) {
        int j = tid - 128;
        float s = hw.ob[j];
        for (int i = 0; i < 32; ++i)
            s = fmaf(acc[b * 32 + i] * (1.f / 1024.f), hw.ow[i * 32 + j], s);
        v96[j] = s;
    }
    __syncthreads();
    if (tid < 64) {
        float s = hw.head_b[tid];
        for (int i = 0; i < 128; ++i)
            s = fmaf(yv[i], hw.head_w[i * 64 + tid], s);
        v96[32 + tid] = s;
    }
    __syncthreads();
    {
        float s = hw.f1b[tid];
        for (int i = 0; i < 96; ++i)
            s = fmaf(v96[i], hw.f1w[i * 256 + tid], s);
        h1[tid] = fmaxf(s, 0.f);
    }
    __syncthreads();
    {
        float s = hw.f2b[tid];
        for (int i = 0; i < 256; ++i)
            s = fmaf(h1[i], hw.f2w[i * 256 + tid], s);
        h2[tid] = fmaxf(s, 0.f);
    }
    __syncthreads();
    if (tid < 128) {
        float s = hw.r1b[tid];
        for (int i = 0; i < 256; ++i)
            s = fmaf(h2[i], hw.r1w[i * 128 + tid], s);
        h3[tid] = fmaxf(s, 0.f);
    }
    __syncthreads();
    if (tid < 10) {
        float s = hw.r2b[tid];
        for (int i = 0; i < 128; ++i)
            s = fmaf(h3[i], hw.r2w[i * 10 + tid], s);
        out[b * 10 + tid] = s;
    }
}

// ---------------------------------------------------------------------------
extern "C" void kernel_launch(void* const* d_in, const int* in_sizes, int n_in,
                              void* d_out, int out_size, void* d_ws, size_t ws_size,
                              hipStream_t stream)
{
    const float* x  = (const float*)d_in[0];
    const float* pw = (const float*)d_in[1];
    const float* pb = (const float*)d_in[2];

    // tcn weights: [5..22] = 3 blocks x (c1w,c1b,c2w,c2b,dw,db)
    const float* c1w0 = (const float*)d_in[5];  const float* c1b0 = (const float*)d_in[6];
    const float* c2w0 = (const float*)d_in[7];  const float* c2b0 = (const float*)d_in[8];
    const float* dw0  = (const float*)d_in[9];  const float* db0  = (const float*)d_in[10];
    const float* c1w1 = (const float*)d_in[11]; const float* c1b1 = (const float*)d_in[12];
    const float* c2w1 = (const float*)d_in[13]; const float* c2b1 = (const float*)d_in[14];
    const float* dw1  = (const float*)d_in[15]; const float* db1  = (const float*)d_in[16];
    const float* c1w2 = (const float*)d_in[17]; const float* c1b2 = (const float*)d_in[18];
    const float* c2w2 = (const float*)d_in[19]; const float* c2b2 = (const float*)d_in[20];
    const float* dw2  = (const float*)d_in[21]; const float* db2  = (const float*)d_in[22];

    HeadW hw = { (const float*)d_in[3],  (const float*)d_in[4],
                 (const float*)d_in[23], (const float*)d_in[24],
                 (const float*)d_in[25], (const float*)d_in[26],
                 (const float*)d_in[27], (const float*)d_in[28],
                 (const float*)d_in[29], (const float*)d_in[30],
                 (const float*)d_in[31], (const float*)d_in[32] };

    float* W   = (float*)d_ws;
    float* h   = W + WS_H;
    float* sq  = W + WS_SQ;
    float* acc = W + WS_ACC;
    float* wT  = W + WS_WT;
    float* a0  = W + WS_A0;
    float* o0  = W + WS_O0;
    float* a1  = W + WS_A1;
    float* o1  = W + WS_O1;
    float* a2  = W + WS_A2;
    float* y   = W + WS_Y;

    WSegs S;
    const float* srcs[9] = {c1w0, c2w0, dw0, c1w1, c2w1, dw1, c1w2, c2w2, dw2};
    const int k3s[9]   = {24, 96, 8, 96, 192, 32, 192, 384, 64};
    const int col2[9]  = {5, 5, 5, 6, 6, 6, 7, 7, 7};
    const int offs[10] = {WT_C1_0, WT_C2_0, WT_DW0, WT_C1_1, WT_C2_1, WT_DW1,
                          WT_C1_2, WT_C2_2, WT_DW2, WT_TOTAL};
    for (int i = 0; i < 9; ++i) { S.src[i] = srcs[i]; S.k3[i] = k3s[i]; S.colog2[i] = col2[i]; }
    for (int i = 0; i < 10; ++i) S.off[i] = offs[i];

    k_project<<<(B_ * T_ * LH_) / 256, 256, 0, stream>>>(x, pw, pb, h, sq, acc);
    k_wT<<<(WT_TOTAL + 255) / 256, 256, 0, stream>>>(S, wT);

    // TCN stages (x row offsets: a0 t0=997, o0 t0=999, a1 t0=1003, o1 t0=1007,
    // a2 t0=1015, y t=1023)
    k_conv<8, 32, 1, 27><<<dim3(4, B_), 256, 0, stream>>>(
        x, T_ * C_, 995, wT + WT_C1_0, c1b0, a0);
    k_convres<32, 32, 1, 25, 8><<<dim3(4, B_), 256, 0, stream>>>(
        a0, 27 * 32, wT + WT_C2_0, c2b0, x, T_ * C_, 999, wT + WT_DW0, db0, o0);
    k_conv<32, 64, 2, 21><<<dim3(6, B_), 256, 0, stream>>>(
        o0, 25 * 32, 0, wT + WT_C1_1, c1b1, a1);
    k_convres<64, 64, 2, 17, 32><<<dim3(5, B_), 256, 0, stream>>>(
        a1, 21 * 64, wT + WT_C2_1, c2b1, o0, 25 * 32, 8, wT + WT_DW1, db1, o1);
    k_conv<64, 128, 4, 9><<<dim3(5, B_), 256, 0, stream>>>(
        o1, 17 * 64, 0, wT + WT_C1_2, c1b2, a2);
    k_convres<128, 128, 4, 1, 64><<<dim3(1, B_), 256, 0, stream>>>(
        a2, 9 * 128, wT + WT_C2_2, c2b2, o1, 17 * 64, 16, wT + WT_DW2, db2, y);

    k_laplace<<<(B_ * T_) / 8, 256, 0, stream>>>(h, sq, acc);
    k_head<<<B_, 256, 0, stream>>>(y, acc, hw, (float*)d_out);
}